// Round 3
// baseline (3828.532 us; speedup 1.0000x reference)
//
#include <hip/hip_runtime.h>
#include <math.h>

// ---------------- workspace layout (float offsets) ----------------
#define VS 131072ull   // vector-column stride (4096 batches * 32 vectors)
#define SB 65536ull    // samples per chain class (big / small)

#define OXV  0ull                    // xvec[143][VS]
#define OFM  18743296ull             // fmag[143][VS]
#define OZ3B 0ull                    // z3 big [476][SB]   (reuses xvec/fmag region)
#define OZ3S 31195136ull             // z3 small [68][SB]
#define OB   37486592ull
#define OZ2B OB                      // z2 big [980][SB]
#define OZ2S (OB + 64225280ull)      // z2 small [140][SB]
#define OZ4B OB                      // z4 big [224][SB]   (reuses z2 region)
#define OZ4S (OB + 14680064ull)      // z4 small [32][SB]
#define OS   110886912ull
#define OS1B OS                      // stats1 big: mu[16][SB], inv[16][SB]
#define OS1S (OS + 2097152ull)       // stats1 small: mu[4], inv[4]
#define OS2B (OS + 2621440ull)       // stats2 big: mu[28], inv[28]
#define OS2S (OS + 6291456ull)
#define OS3B (OS + 6815744ull)
#define OS3S (OS + 10485760ull)
#define OTW  (OS + 11010048ull)      // twiddle table [72][143] float2
// total = OTW + 20592 = 121,917,552 floats = 466 MB

// ---------------- k_gather: x -> xvec columns; block 4096 builds twiddles ----
__global__ __launch_bounds__(256) void k_gather(const float* __restrict__ x,
                                                float* __restrict__ ws) {
  const int b = blockIdx.x;
  if (b < 4096) {
    const float* xb = x + (size_t)b * 9152;
    const int base = b * 32;
    for (int i = threadIdx.x; i < 9152; i += 256) {
      float v = xb[i];
      int c = i >> 6, pos = i & 63;
      if (pos >= 24 && pos < 40)
        ws[OXV + (size_t)c * VS + base + (pos - 24)] = v;
      int wc = pos & 7;
      if (wc == 3 || wc == 4)
        ws[OXV + (size_t)c * VS + base + 16 + ((pos >> 3) << 1) + (wc - 3)] = v;
    }
  } else {
    float* tw = ws + OTW;
    for (int i = threadIdx.x; i < 10296; i += 256) {
      int k = i / 143, n = i - k * 143;
      int e = (k * n) % 143;
      float ang = 6.2831853071795864769f * (float)e / 143.0f;
      float s, c;
      sincosf(ang, &s, &c);
      tw[2 * i] = c;
      tw[2 * i + 1] = s;
    }
  }
}

// ---------------- k_dft: lane = vector, column in VGPRs, uniform twiddles ----
__global__ __launch_bounds__(256, 2) void k_dft(float* __restrict__ ws) {
  const float* __restrict__ xvec = ws + OXV;
  const float* __restrict__ tw = ws + OTW;
  float* __restrict__ fmag = ws + OFM;
  const int v = blockIdx.x * 256 + threadIdx.x;

  float xr[143];
#pragma unroll
  for (int n = 0; n < 143; ++n) xr[n] = xvec[(size_t)n * VS + v];

  for (int k = 0; k < 72; ++k) {
    const float* __restrict__ twk = tw + k * 286;   // wave-uniform -> s_load
    float re = 0.f, im = 0.f;
#pragma unroll
    for (int n = 0; n < 143; ++n) {
      re = fmaf(xr[n], twk[2 * n], re);
      im = fmaf(xr[n], twk[2 * n + 1], im);
    }
    float m = sqrtf(re * re + im * im);
    fmag[(size_t)k * VS + v] = m;
    if (k) fmag[(size_t)(143 - k) * VS + v] = m;
  }
}

// sample -> input vector columns
__device__ __forceinline__ void vcols(int d, int& va, int& vb, int& bi, int& u) {
  bi = d >> 4;
  u = d & 15;
  int base = bi * 32;
  va = (u < 8) ? (base + ((u >> 2) << 3) + ((u & 3) << 1))
               : (base + 16 + ((u & 7) << 1));
  vb = va + 1;
}

// wave mapping: 512 blocks x 4 waves; 2 big + 2 small waves per block (parity-
// interleaved so each SIMD gets a mix); lane owns one sample.
__device__ __forceinline__ bool wave_map(int& d) {
  int w = threadIdx.x >> 6, lane = threadIdx.x & 63;
  bool big = (((w + blockIdx.x) & 1) == 0);
  int r = w >> 1;
  d = blockIdx.x * 128 + r * 64 + lane;
  return big;
}

// ---------------- k_c1: conv1 -> LN1 stats only (no z1 store) ----------------
__global__ __launch_bounds__(256) void k_c1(float* __restrict__ ws,
                                            const float* __restrict__ w1,
                                            const float* __restrict__ f1) {
  __shared__ float lw1[96], lf1[24];
  for (int i = threadIdx.x; i < 96; i += 256) lw1[i] = w1[i];
  for (int i = threadIdx.x; i < 24; i += 256) lf1[i] = f1[i];
  __syncthreads();

  int d;
  const bool big = wave_map(d);
  int va, vb, bi, u;
  vcols(d, va, vb, bi, u);
  const float* __restrict__ src = ws + (big ? OXV : OFM);

  if (big) {
    float sum[16], sq[16];
#pragma unroll
    for (int c = 0; c < 16; ++c) { sum[c] = 0.f; sq[c] = 0.f; }
    for (int p = 0; p < 71; ++p) {
      float a0 = src[(size_t)(2 * p) * VS + va];
      float a1 = src[(size_t)(2 * p + 1) * VS + va];
      float a2 = src[(size_t)(2 * p + 2) * VS + va];
      float b0 = src[(size_t)(2 * p) * VS + vb];
      float b1 = src[(size_t)(2 * p + 1) * VS + vb];
      float b2 = src[(size_t)(2 * p + 2) * VS + vb];
#pragma unroll
      for (int c = 0; c < 16; ++c) {
        const float* wp = lw1 + c * 6;
        float v = a0 * wp[0];
        v = fmaf(a1, wp[1], v);
        v = fmaf(a2, wp[2], v);
        v = fmaf(b0, wp[3], v);
        v = fmaf(b1, wp[4], v);
        v = fmaf(b2, wp[5], v);
        sum[c] += v;
        sq[c] = fmaf(v, v, sq[c]);
      }
    }
#pragma unroll
    for (int c = 0; c < 16; ++c) {
      float mu = sum[c] * (1.0f / 71.0f);
      float var = sq[c] * (1.0f / 71.0f) - mu * mu;
      ws[OS1B + (size_t)c * SB + d] = mu;
      ws[OS1B + (size_t)(16 + c) * SB + d] = rsqrtf(var + 1e-5f);
    }
  } else {
    float sum[4], sq[4];
#pragma unroll
    for (int c = 0; c < 4; ++c) { sum[c] = 0.f; sq[c] = 0.f; }
    for (int p = 0; p < 71; ++p) {
      float a0 = src[(size_t)(2 * p) * VS + va];
      float a1 = src[(size_t)(2 * p + 1) * VS + va];
      float a2 = src[(size_t)(2 * p + 2) * VS + va];
      float b0 = src[(size_t)(2 * p) * VS + vb];
      float b1 = src[(size_t)(2 * p + 1) * VS + vb];
      float b2 = src[(size_t)(2 * p + 2) * VS + vb];
#pragma unroll
      for (int c = 0; c < 4; ++c) {
        const float* wp = lf1 + c * 6;
        float v = a0 * wp[0];
        v = fmaf(a1, wp[1], v);
        v = fmaf(a2, wp[2], v);
        v = fmaf(b0, wp[3], v);
        v = fmaf(b1, wp[4], v);
        v = fmaf(b2, wp[5], v);
        sum[c] += v;
        sq[c] = fmaf(v, v, sq[c]);
      }
    }
#pragma unroll
    for (int c = 0; c < 4; ++c) {
      float mu = sum[c] * (1.0f / 71.0f);
      float var = sq[c] * (1.0f / 71.0f) - mu * mu;
      ws[OS1S + (size_t)c * SB + d] = mu;
      ws[OS1S + (size_t)(4 + c) * SB + d] = rsqrtf(var + 1e-5f);
    }
  }
}

// -------- k_c2: conv1 (recomputed) + LN1-apply + conv2 + LN2 stats -> z2 ----
__global__ __launch_bounds__(256, 2) void k_c2(float* __restrict__ ws,
                                               const float* __restrict__ w1,
                                               const float* __restrict__ w2,
                                               const float* __restrict__ f1,
                                               const float* __restrict__ f2,
                                               const float* __restrict__ l1g,
                                               const float* __restrict__ l1b) {
  __shared__ float lw1[96], lw2[1344], lf1[24], lf2[48], lg1[71], lb1[71];
  for (int i = threadIdx.x; i < 96; i += 256) lw1[i] = w1[i];
  for (int i = threadIdx.x; i < 1344; i += 256) lw2[i] = w2[i];
  for (int i = threadIdx.x; i < 24; i += 256) lf1[i] = f1[i];
  for (int i = threadIdx.x; i < 48; i += 256) lf2[i] = f2[i];
  for (int i = threadIdx.x; i < 71; i += 256) { lg1[i] = l1g[i]; lb1[i] = l1b[i]; }
  __syncthreads();

  int d;
  const bool big = wave_map(d);
  int va, vb, bi, u;
  vcols(d, va, vb, bi, u);
  const float* __restrict__ src = ws + (big ? OXV : OFM);

  if (big) {
    float mu1[16], inv1[16];
#pragma unroll
    for (int c = 0; c < 16; ++c) {
      mu1[c] = ws[OS1B + (size_t)c * SB + d];
      inv1[c] = ws[OS1B + (size_t)(16 + c) * SB + d];
    }
    float sum2[28], sq2[28];
#pragma unroll
    for (int c = 0; c < 28; ++c) { sum2[c] = 0.f; sq2[c] = 0.f; }

    for (int p = 0; p < 35; ++p) {
      float xa[7], xb[7];
#pragma unroll
      for (int t = 0; t < 7; ++t) {
        xa[t] = src[(size_t)(4 * p + t) * VS + va];
        xb[t] = src[(size_t)(4 * p + t) * VS + vb];
      }
      float z1v[3][16];
#pragma unroll
      for (int r = 0; r < 3; ++r) {
        const int ip = 2 * p + r;
        const float gg = lg1[ip], bb = lb1[ip];
#pragma unroll
        for (int c = 0; c < 16; ++c) {
          const float* wp = lw1 + c * 6;
          float v = xa[2 * r] * wp[0];
          v = fmaf(xa[2 * r + 1], wp[1], v);
          v = fmaf(xa[2 * r + 2], wp[2], v);
          v = fmaf(xb[2 * r], wp[3], v);
          v = fmaf(xb[2 * r + 1], wp[4], v);
          v = fmaf(xb[2 * r + 2], wp[5], v);
          float n = (v - mu1[c]) * inv1[c];
          z1v[r][c] = fmaxf(fmaf(n, gg, bb), 0.f);
        }
      }
#pragma unroll
      for (int co = 0; co < 28; ++co) {
        const float* wp = lw2 + co * 48;
        float acc = 0.f;
#pragma unroll
        for (int ci = 0; ci < 16; ++ci) {
          acc = fmaf(z1v[0][ci], wp[ci * 3 + 0], acc);
          acc = fmaf(z1v[1][ci], wp[ci * 3 + 1], acc);
          acc = fmaf(z1v[2][ci], wp[ci * 3 + 2], acc);
        }
        ws[OZ2B + (size_t)(co * 35 + p) * SB + d] = acc;
        sum2[co] += acc;
        sq2[co] = fmaf(acc, acc, sq2[co]);
      }
    }
#pragma unroll
    for (int c = 0; c < 28; ++c) {
      float mu = sum2[c] * (1.0f / 35.0f);
      float var = sq2[c] * (1.0f / 35.0f) - mu * mu;
      ws[OS2B + (size_t)c * SB + d] = mu;
      ws[OS2B + (size_t)(28 + c) * SB + d] = rsqrtf(var + 1e-5f);
    }
  } else {
    float mu1[4], inv1[4];
#pragma unroll
    for (int c = 0; c < 4; ++c) {
      mu1[c] = ws[OS1S + (size_t)c * SB + d];
      inv1[c] = ws[OS1S + (size_t)(4 + c) * SB + d];
    }
    float sum2[4], sq2[4];
#pragma unroll
    for (int c = 0; c < 4; ++c) { sum2[c] = 0.f; sq2[c] = 0.f; }

    for (int p = 0; p < 35; ++p) {
      float xa[7], xb[7];
#pragma unroll
      for (int t = 0; t < 7; ++t) {
        xa[t] = src[(size_t)(4 * p + t) * VS + va];
        xb[t] = src[(size_t)(4 * p + t) * VS + vb];
      }
      float z1v[3][4];
#pragma unroll
      for (int r = 0; r < 3; ++r) {
        const int ip = 2 * p + r;
        const float gg = lg1[ip], bb = lb1[ip];
#pragma unroll
        for (int c = 0; c < 4; ++c) {
          const float* wp = lf1 + c * 6;
          float v = xa[2 * r] * wp[0];
          v = fmaf(xa[2 * r + 1], wp[1], v);
          v = fmaf(xa[2 * r + 2], wp[2], v);
          v = fmaf(xb[2 * r], wp[3], v);
          v = fmaf(xb[2 * r + 1], wp[4], v);
          v = fmaf(xb[2 * r + 2], wp[5], v);
          float n = (v - mu1[c]) * inv1[c];
          z1v[r][c] = fmaxf(fmaf(n, gg, bb), 0.f);
        }
      }
#pragma unroll
      for (int co = 0; co < 4; ++co) {
        const float* wp = lf2 + co * 12;
        float acc = 0.f;
#pragma unroll
        for (int ci = 0; ci < 4; ++ci) {
          acc = fmaf(z1v[0][ci], wp[ci * 3 + 0], acc);
          acc = fmaf(z1v[1][ci], wp[ci * 3 + 1], acc);
          acc = fmaf(z1v[2][ci], wp[ci * 3 + 2], acc);
        }
        ws[OZ2S + (size_t)(co * 35 + p) * SB + d] = acc;
        sum2[co] += acc;
        sq2[co] = fmaf(acc, acc, sq2[co]);
      }
    }
#pragma unroll
    for (int c = 0; c < 4; ++c) {
      float mu = sum2[c] * (1.0f / 35.0f);
      float var = sq2[c] * (1.0f / 35.0f) - mu * mu;
      ws[OS2S + (size_t)c * SB + d] = mu;
      ws[OS2S + (size_t)(4 + c) * SB + d] = rsqrtf(var + 1e-5f);
    }
  }
}

// -------- k_c3: LN2-apply + conv3 + LN3 stats -> z3 --------------------------
__global__ __launch_bounds__(256, 2) void k_c3(float* __restrict__ ws,
                                               const float* __restrict__ w3,
                                               const float* __restrict__ f3,
                                               const float* __restrict__ l2g,
                                               const float* __restrict__ l2b) {
  __shared__ float lw3[2352], lf3[48], lg2[35], lb2[35];
  for (int i = threadIdx.x; i < 2352; i += 256) lw3[i] = w3[i];
  for (int i = threadIdx.x; i < 48; i += 256) lf3[i] = f3[i];
  for (int i = threadIdx.x; i < 35; i += 256) { lg2[i] = l2g[i]; lb2[i] = l2b[i]; }
  __syncthreads();

  int d;
  const bool big = wave_map(d);

  if (big) {
    float mu2[28], inv2[28];
#pragma unroll
    for (int c = 0; c < 28; ++c) {
      mu2[c] = ws[OS2B + (size_t)c * SB + d];
      inv2[c] = ws[OS2B + (size_t)(28 + c) * SB + d];
    }
    float sum3[28], sq3[28];
#pragma unroll
    for (int c = 0; c < 28; ++c) { sum3[c] = 0.f; sq3[c] = 0.f; }

    for (int p = 0; p < 17; ++p) {
      float win[3][28];
#pragma unroll
      for (int r = 0; r < 3; ++r) {
        const int ip = 2 * p + r;
        const float gg = lg2[ip], bb = lb2[ip];
#pragma unroll
        for (int ci = 0; ci < 28; ++ci) {
          float raw = ws[OZ2B + (size_t)(ci * 35 + ip) * SB + d];
          float n = (raw - mu2[ci]) * inv2[ci];
          win[r][ci] = fmaxf(fmaf(n, gg, bb), 0.f);
        }
      }
#pragma unroll
      for (int co = 0; co < 28; ++co) {
        const float* wp = lw3 + co * 84;
        float acc = 0.f;
#pragma unroll
        for (int ci = 0; ci < 28; ++ci) {
          acc = fmaf(win[0][ci], wp[ci * 3 + 0], acc);
          acc = fmaf(win[1][ci], wp[ci * 3 + 1], acc);
          acc = fmaf(win[2][ci], wp[ci * 3 + 2], acc);
        }
        ws[OZ3B + (size_t)(co * 17 + p) * SB + d] = acc;
        sum3[co] += acc;
        sq3[co] = fmaf(acc, acc, sq3[co]);
      }
    }
#pragma unroll
    for (int c = 0; c < 28; ++c) {
      float mu = sum3[c] * (1.0f / 17.0f);
      float var = sq3[c] * (1.0f / 17.0f) - mu * mu;
      ws[OS3B + (size_t)c * SB + d] = mu;
      ws[OS3B + (size_t)(28 + c) * SB + d] = rsqrtf(var + 1e-5f);
    }
  } else {
    float mu2[4], inv2[4];
#pragma unroll
    for (int c = 0; c < 4; ++c) {
      mu2[c] = ws[OS2S + (size_t)c * SB + d];
      inv2[c] = ws[OS2S + (size_t)(4 + c) * SB + d];
    }
    float sum3[4], sq3[4];
#pragma unroll
    for (int c = 0; c < 4; ++c) { sum3[c] = 0.f; sq3[c] = 0.f; }

    for (int p = 0; p < 17; ++p) {
      float win[3][4];
#pragma unroll
      for (int r = 0; r < 3; ++r) {
        const int ip = 2 * p + r;
        const float gg = lg2[ip], bb = lb2[ip];
#pragma unroll
        for (int ci = 0; ci < 4; ++ci) {
          float raw = ws[OZ2S + (size_t)(ci * 35 + ip) * SB + d];
          float n = (raw - mu2[ci]) * inv2[ci];
          win[r][ci] = fmaxf(fmaf(n, gg, bb), 0.f);
        }
      }
#pragma unroll
      for (int co = 0; co < 4; ++co) {
        const float* wp = lf3 + co * 12;
        float acc = 0.f;
#pragma unroll
        for (int ci = 0; ci < 4; ++ci) {
          acc = fmaf(win[0][ci], wp[ci * 3 + 0], acc);
          acc = fmaf(win[1][ci], wp[ci * 3 + 1], acc);
          acc = fmaf(win[2][ci], wp[ci * 3 + 2], acc);
        }
        ws[OZ3S + (size_t)(co * 17 + p) * SB + d] = acc;
        sum3[co] += acc;
        sq3[co] = fmaf(acc, acc, sq3[co]);
      }
    }
#pragma unroll
    for (int c = 0; c < 4; ++c) {
      float mu = sum3[c] * (1.0f / 17.0f);
      float var = sq3[c] * (1.0f / 17.0f) - mu * mu;
      ws[OS3S + (size_t)c * SB + d] = mu;
      ws[OS3S + (size_t)(4 + c) * SB + d] = rsqrtf(var + 1e-5f);
    }
  }
}

// -------- k_c4: LN3-apply + conv4 + LN4 + ReLU + final store ----------------
__global__ __launch_bounds__(256, 2) void k_c4(float* __restrict__ ws,
                                               const float* __restrict__ w4,
                                               const float* __restrict__ f4,
                                               const float* __restrict__ l3g,
                                               const float* __restrict__ l3b,
                                               const float* __restrict__ l4g,
                                               const float* __restrict__ l4b,
                                               float* __restrict__ out) {
  __shared__ float lw4[2352], lf4[48], lg3[17], lb3[17], lg4[8], lb4[8];
  for (int i = threadIdx.x; i < 2352; i += 256) lw4[i] = w4[i];
  for (int i = threadIdx.x; i < 48; i += 256) lf4[i] = f4[i];
  for (int i = threadIdx.x; i < 17; i += 256) { lg3[i] = l3g[i]; lb3[i] = l3b[i]; }
  if (threadIdx.x < 8) { lg4[threadIdx.x] = l4g[threadIdx.x]; lb4[threadIdx.x] = l4b[threadIdx.x]; }
  __syncthreads();

  int d;
  const bool big = wave_map(d);
  const int bi = d >> 4, u = d & 15;

  if (big) {
    float mu3[28], inv3[28];
#pragma unroll
    for (int c = 0; c < 28; ++c) {
      mu3[c] = ws[OS3B + (size_t)c * SB + d];
      inv3[c] = ws[OS3B + (size_t)(28 + c) * SB + d];
    }
    float sum4[28], sq4[28];
#pragma unroll
    for (int c = 0; c < 28; ++c) { sum4[c] = 0.f; sq4[c] = 0.f; }

    for (int p = 0; p < 8; ++p) {
      float win[3][28];
#pragma unroll
      for (int r = 0; r < 3; ++r) {
        const int ip = 2 * p + r;
        const float gg = lg3[ip], bb = lb3[ip];
#pragma unroll
        for (int ci = 0; ci < 28; ++ci) {
          float raw = ws[OZ3B + (size_t)(ci * 17 + ip) * SB + d];
          float n = (raw - mu3[ci]) * inv3[ci];
          win[r][ci] = fmaxf(fmaf(n, gg, bb), 0.f);
        }
      }
#pragma unroll
      for (int co = 0; co < 28; ++co) {
        const float* wp = lw4 + co * 84;
        float acc = 0.f;
#pragma unroll
        for (int ci = 0; ci < 28; ++ci) {
          acc = fmaf(win[0][ci], wp[ci * 3 + 0], acc);
          acc = fmaf(win[1][ci], wp[ci * 3 + 1], acc);
          acc = fmaf(win[2][ci], wp[ci * 3 + 2], acc);
        }
        ws[OZ4B + (size_t)(co * 8 + p) * SB + d] = acc;
        sum4[co] += acc;
        sq4[co] = fmaf(acc, acc, sq4[co]);
      }
    }
    // epilogue: LN4 + relu + coalesced 32B stores
#pragma unroll
    for (int co = 0; co < 28; ++co) {
      float mu = sum4[co] * 0.125f;
      float var = sq4[co] * 0.125f - mu * mu;
      float inv = rsqrtf(var + 1e-5f);
      float o[8];
#pragma unroll
      for (int p = 0; p < 8; ++p) {
        float raw = ws[OZ4B + (size_t)(co * 8 + p) * SB + d];
        float n = (raw - mu) * inv;
        o[p] = fmaxf(fmaf(n, lg4[p], lb4[p]), 0.f);
      }
      const int ch = (u < 8) ? co : (28 + co);
      float* op = out + (size_t)bi * 4096 + (size_t)ch * 64 + (size_t)(u & 7) * 8;
      *(float4*)(op) = make_float4(o[0], o[1], o[2], o[3]);
      *(float4*)(op + 4) = make_float4(o[4], o[5], o[6], o[7]);
    }
  } else {
    float mu3[4], inv3[4];
#pragma unroll
    for (int c = 0; c < 4; ++c) {
      mu3[c] = ws[OS3S + (size_t)c * SB + d];
      inv3[c] = ws[OS3S + (size_t)(4 + c) * SB + d];
    }
    float sum4[4], sq4[4];
#pragma unroll
    for (int c = 0; c < 4; ++c) { sum4[c] = 0.f; sq4[c] = 0.f; }

    for (int p = 0; p < 8; ++p) {
      float win[3][4];
#pragma unroll
      for (int r = 0; r < 3; ++r) {
        const int ip = 2 * p + r;
        const float gg = lg3[ip], bb = lb3[ip];
#pragma unroll
        for (int ci = 0; ci < 4; ++ci) {
          float raw = ws[OZ3S + (size_t)(ci * 17 + ip) * SB + d];
          float n = (raw - mu3[ci]) * inv3[ci];
          win[r][ci] = fmaxf(fmaf(n, gg, bb), 0.f);
        }
      }
#pragma unroll
      for (int co = 0; co < 4; ++co) {
        const float* wp = lf4 + co * 12;
        float acc = 0.f;
#pragma unroll
        for (int ci = 0; ci < 4; ++ci) {
          acc = fmaf(win[0][ci], wp[ci * 3 + 0], acc);
          acc = fmaf(win[1][ci], wp[ci * 3 + 1], acc);
          acc = fmaf(win[2][ci], wp[ci * 3 + 2], acc);
        }
        ws[OZ4S + (size_t)(co * 8 + p) * SB + d] = acc;
        sum4[co] += acc;
        sq4[co] = fmaf(acc, acc, sq4[co]);
      }
    }
#pragma unroll
    for (int co = 0; co < 4; ++co) {
      float mu = sum4[co] * 0.125f;
      float var = sq4[co] * 0.125f - mu * mu;
      float inv = rsqrtf(var + 1e-5f);
      float o[8];
#pragma unroll
      for (int p = 0; p < 8; ++p) {
        float raw = ws[OZ4S + (size_t)(co * 8 + p) * SB + d];
        float n = (raw - mu) * inv;
        o[p] = fmaxf(fmaf(n, lg4[p], lb4[p]), 0.f);
      }
      const int ch = (u < 8) ? (56 + co) : (60 + co);
      float* op = out + (size_t)bi * 4096 + (size_t)ch * 64 + (size_t)(u & 7) * 8;
      *(float4*)(op) = make_float4(o[0], o[1], o[2], o[3]);
      *(float4*)(op + 4) = make_float4(o[4], o[5], o[6], o[7]);
    }
  }
}

extern "C" void kernel_launch(void* const* d_in, const int* in_sizes, int n_in,
                              void* d_out, int out_size, void* d_ws, size_t ws_size,
                              hipStream_t stream) {
  const float* x   = (const float*)d_in[0];
  const float* w1  = (const float*)d_in[1];
  const float* w2  = (const float*)d_in[2];
  const float* w3  = (const float*)d_in[3];
  const float* w4  = (const float*)d_in[4];
  const float* f1  = (const float*)d_in[5];
  const float* f2  = (const float*)d_in[6];
  const float* f3  = (const float*)d_in[7];
  const float* f4  = (const float*)d_in[8];
  const float* l1g = (const float*)d_in[9];
  const float* l1b = (const float*)d_in[10];
  const float* l2g = (const float*)d_in[11];
  const float* l2b = (const float*)d_in[12];
  const float* l3g = (const float*)d_in[13];
  const float* l3b = (const float*)d_in[14];
  const float* l4g = (const float*)d_in[15];
  const float* l4b = (const float*)d_in[16];
  float* out = (float*)d_out;
  float* ws = (float*)d_ws;   // needs 121,917,552 floats = 466 MB

  k_gather<<<4097, 256, 0, stream>>>(x, ws);
  k_dft<<<512, 256, 0, stream>>>(ws);
  k_c1<<<512, 256, 0, stream>>>(ws, w1, f1);
  k_c2<<<512, 256, 0, stream>>>(ws, w1, w2, f1, f2, l1g, l1b);
  k_c3<<<512, 256, 0, stream>>>(ws, w3, f3, l2g, l2b);
  k_c4<<<512, 256, 0, stream>>>(ws, w4, f4, l3g, l3b, l4g, l4b, out);
}

// Round 4
// 2517.854 us; speedup vs baseline: 1.5206x; 1.5206x over previous
//
#include <hip/hip_runtime.h>
#include <math.h>

typedef _Float16 h16;

#define NS 65536      // samples per class (big / small)
#define VSTR 131072   // xvec/fmag column count (4096 batches * 32 vectors)

// ---------------- k_gather: x -> xvec columns (fp32); block 4096 builds twiddles ----
__global__ __launch_bounds__(256) void k_gather(const float* __restrict__ x,
                                                float* __restrict__ xv,
                                                float* __restrict__ tw) {
  const int b = blockIdx.x;
  if (b < 4096) {
    const float* xb = x + (size_t)b * 9152;
    const int base = b * 32;
    for (int i = threadIdx.x; i < 9152; i += 256) {
      float v = xb[i];
      int c = i >> 6, pos = i & 63;
      if (pos >= 24 && pos < 40)
        xv[(size_t)c * VSTR + base + (pos - 24)] = v;
      int wc = pos & 7;
      if (wc == 3 || wc == 4)
        xv[(size_t)c * VSTR + base + 16 + ((pos >> 3) << 1) + (wc - 3)] = v;
    }
  } else {
    for (int i = threadIdx.x; i < 10296; i += 256) {
      int k = i / 143, n = i - k * 143;
      int e = (k * n) % 143;
      float ang = 6.2831853071795864769f * (float)e / 143.0f;
      float s, c;
      sincosf(ang, &s, &c);
      tw[2 * i] = c;
      tw[2 * i + 1] = s;
    }
  }
}

// ---------------- k_dft: lane = vector, column in VGPRs, uniform twiddles ----
__global__ __launch_bounds__(256, 2) void k_dft(const float* __restrict__ xv,
                                                const float* __restrict__ tw,
                                                h16* __restrict__ fm) {
  const int v = blockIdx.x * 256 + threadIdx.x;
  float xr[143];
#pragma unroll
  for (int n = 0; n < 143; ++n) xr[n] = xv[(size_t)n * VSTR + v];

  for (int k = 0; k < 72; ++k) {
    const float* __restrict__ twk = tw + k * 286;
    float re = 0.f, im = 0.f;
#pragma unroll
    for (int n = 0; n < 143; ++n) {
      re = fmaf(xr[n], twk[2 * n], re);
      im = fmaf(xr[n], twk[2 * n + 1], im);
    }
    float m = sqrtf(re * re + im * im);
    fm[(size_t)k * VSTR + v] = (h16)m;
    if (k) fm[(size_t)(143 - k) * VSTR + v] = (h16)m;
  }
}

// shared sample mapping: blocks alternate big/small; 64 samples per block,
// all 4 waves see the same samples (lane = sample), wave = output-channel group.
__device__ __forceinline__ void smap(int& d, bool& big, int& w, int& va, int& vb,
                                     int& bi, int& u) {
  int lane = threadIdx.x & 63;
  w = __builtin_amdgcn_readfirstlane(threadIdx.x >> 6);
  int blk = blockIdx.x;
  big = (blk & 1) == 0;
  d = (blk >> 1) * 64 + lane;
  bi = d >> 4;
  u = d & 15;
  va = (u < 8) ? bi * 32 + ((u >> 2) << 3) + ((u & 3) << 1)
               : bi * 32 + 16 + ((u & 7) << 1);
  vb = va + 1;
}

// ---------------- k_c1: conv1 -> LN1 stats (no z1 store) ----------------
__global__ __launch_bounds__(256, 2) void k_c1(const float* __restrict__ xv,
                                               const h16* __restrict__ fm,
                                               const float* __restrict__ w1,
                                               const float* __restrict__ f1,
                                               float* __restrict__ s1) {
  int d, w, va, vb, bi, u; bool big;
  smap(d, big, w, va, vb, bi, u);

  if (big) {
    float sum[4] = {0, 0, 0, 0}, sq[4] = {0, 0, 0, 0};
    float A0 = xv[va], B0 = xv[vb];
    for (int p = 0; p < 71; ++p) {
      float A1 = xv[(size_t)(2 * p + 1) * VSTR + va];
      float A2 = xv[(size_t)(2 * p + 2) * VSTR + va];
      float B1 = xv[(size_t)(2 * p + 1) * VSTR + vb];
      float B2 = xv[(size_t)(2 * p + 2) * VSTR + vb];
#pragma unroll
      for (int j = 0; j < 4; ++j) {
        const float* wp = w1 + (4 * w + j) * 6;
        float v = A0 * wp[0];
        v = fmaf(A1, wp[1], v); v = fmaf(A2, wp[2], v);
        v = fmaf(B0, wp[3], v); v = fmaf(B1, wp[4], v); v = fmaf(B2, wp[5], v);
        sum[j] += v; sq[j] = fmaf(v, v, sq[j]);
      }
      A0 = A2; B0 = B2;
    }
#pragma unroll
    for (int j = 0; j < 4; ++j) {
      float mu = sum[j] * (1.0f / 71.0f);
      float var = sq[j] * (1.0f / 71.0f) - mu * mu;
      s1[(size_t)(4 * w + j) * NS + d] = mu;
      s1[(size_t)(16 + 4 * w + j) * NS + d] = rsqrtf(var + 1e-5f);
    }
  } else {
    float sum = 0.f, sq = 0.f;
    const float* wp = f1 + w * 6;
    float A0 = (float)fm[va], B0 = (float)fm[vb];
    for (int p = 0; p < 71; ++p) {
      float A1 = (float)fm[(size_t)(2 * p + 1) * VSTR + va];
      float A2 = (float)fm[(size_t)(2 * p + 2) * VSTR + va];
      float B1 = (float)fm[(size_t)(2 * p + 1) * VSTR + vb];
      float B2 = (float)fm[(size_t)(2 * p + 2) * VSTR + vb];
      float v = A0 * wp[0];
      v = fmaf(A1, wp[1], v); v = fmaf(A2, wp[2], v);
      v = fmaf(B0, wp[3], v); v = fmaf(B1, wp[4], v); v = fmaf(B2, wp[5], v);
      sum += v; sq = fmaf(v, v, sq);
      A0 = A2; B0 = B2;
    }
    float mu = sum * (1.0f / 71.0f);
    float var = sq * (1.0f / 71.0f) - mu * mu;
    s1[(size_t)(32 + w) * NS + d] = mu;
    s1[(size_t)(36 + w) * NS + d] = rsqrtf(var + 1e-5f);
  }
}

// -------- k_c2: conv1(recomp) + LN1-apply + conv2 + LN2 stats -> z2 (fp16) ----
__global__ __launch_bounds__(256, 2) void k_c2(const float* __restrict__ xv,
                                               const h16* __restrict__ fm,
                                               const float* __restrict__ w1,
                                               const float* __restrict__ w2,
                                               const float* __restrict__ f1,
                                               const float* __restrict__ f2,
                                               const float* __restrict__ l1g,
                                               const float* __restrict__ l1b,
                                               const float* __restrict__ s1,
                                               h16* __restrict__ z2,
                                               float* __restrict__ s2) {
  int d, w, va, vb, bi, u; bool big;
  smap(d, big, w, va, vb, bi, u);

  if (big) {
    float mu1[16], inv1[16];
#pragma unroll
    for (int c = 0; c < 16; ++c) {
      mu1[c] = s1[(size_t)c * NS + d];
      inv1[c] = s1[(size_t)(16 + c) * NS + d];
    }
    float sum[7] = {0, 0, 0, 0, 0, 0, 0}, sq[7] = {0, 0, 0, 0, 0, 0, 0};
    const int cobase = 7 * w;
    for (int p = 0; p < 35; ++p) {
      float xa[7], xb[7];
#pragma unroll
      for (int t = 0; t < 7; ++t) {
        xa[t] = xv[(size_t)(4 * p + t) * VSTR + va];
        xb[t] = xv[(size_t)(4 * p + t) * VSTR + vb];
      }
      float z1n[3][16];
#pragma unroll
      for (int r = 0; r < 3; ++r) {
        const int ip = 2 * p + r;
        const float gg = l1g[ip], bb = l1b[ip];
#pragma unroll
        for (int c = 0; c < 16; ++c) {
          const float* wp = w1 + c * 6;
          float v = xa[2 * r] * wp[0];
          v = fmaf(xa[2 * r + 1], wp[1], v);
          v = fmaf(xa[2 * r + 2], wp[2], v);
          v = fmaf(xb[2 * r], wp[3], v);
          v = fmaf(xb[2 * r + 1], wp[4], v);
          v = fmaf(xb[2 * r + 2], wp[5], v);
          float n = (v - mu1[c]) * inv1[c];
          z1n[r][c] = fmaxf(fmaf(n, gg, bb), 0.f);
        }
      }
#pragma unroll
      for (int j = 0; j < 7; ++j) {
        const int co = cobase + j;
        const float* wp = w2 + co * 48;
        float acc = 0.f;
#pragma unroll
        for (int ci = 0; ci < 16; ++ci) {
          acc = fmaf(z1n[0][ci], wp[ci * 3 + 0], acc);
          acc = fmaf(z1n[1][ci], wp[ci * 3 + 1], acc);
          acc = fmaf(z1n[2][ci], wp[ci * 3 + 2], acc);
        }
        z2[(size_t)(co * 35 + p) * NS + d] = (h16)acc;
        sum[j] += acc; sq[j] = fmaf(acc, acc, sq[j]);
      }
    }
#pragma unroll
    for (int j = 0; j < 7; ++j) {
      const int co = cobase + j;
      float mu = sum[j] * (1.0f / 35.0f);
      float var = sq[j] * (1.0f / 35.0f) - mu * mu;
      s2[(size_t)co * NS + d] = mu;
      s2[(size_t)(28 + co) * NS + d] = rsqrtf(var + 1e-5f);
    }
  } else {
    float mu1[4], inv1[4];
#pragma unroll
    for (int c = 0; c < 4; ++c) {
      mu1[c] = s1[(size_t)(32 + c) * NS + d];
      inv1[c] = s1[(size_t)(36 + c) * NS + d];
    }
    float sum = 0.f, sq = 0.f;
    const int co = w;
    const float* wpo = f2 + co * 12;
    for (int p = 0; p < 35; ++p) {
      float xa[7], xb[7];
#pragma unroll
      for (int t = 0; t < 7; ++t) {
        xa[t] = (float)fm[(size_t)(4 * p + t) * VSTR + va];
        xb[t] = (float)fm[(size_t)(4 * p + t) * VSTR + vb];
      }
      float acc = 0.f;
#pragma unroll
      for (int r = 0; r < 3; ++r) {
        const int ip = 2 * p + r;
        const float gg = l1g[ip], bb = l1b[ip];
#pragma unroll
        for (int c = 0; c < 4; ++c) {
          const float* wp = f1 + c * 6;
          float v = xa[2 * r] * wp[0];
          v = fmaf(xa[2 * r + 1], wp[1], v);
          v = fmaf(xa[2 * r + 2], wp[2], v);
          v = fmaf(xb[2 * r], wp[3], v);
          v = fmaf(xb[2 * r + 1], wp[4], v);
          v = fmaf(xb[2 * r + 2], wp[5], v);
          float n = (v - mu1[c]) * inv1[c];
          float zr = fmaxf(fmaf(n, gg, bb), 0.f);
          acc = fmaf(zr, wp == wp ? wpo[c * 3 + r] : 0.f, acc);
        }
      }
      z2[(size_t)(980 + co * 35 + p) * NS + d] = (h16)acc;
      sum += acc; sq = fmaf(acc, acc, sq);
    }
    float mu = sum * (1.0f / 35.0f);
    float var = sq * (1.0f / 35.0f) - mu * mu;
    s2[(size_t)(56 + co) * NS + d] = mu;
    s2[(size_t)(60 + co) * NS + d] = rsqrtf(var + 1e-5f);
  }
}

// -------- k_c3: LN2-apply + conv3 + LN3 stats -> z3 (fp16) -------------------
__global__ __launch_bounds__(256, 2) void k_c3(const h16* __restrict__ z2,
                                               const float* __restrict__ w3,
                                               const float* __restrict__ f3,
                                               const float* __restrict__ l2g,
                                               const float* __restrict__ l2b,
                                               const float* __restrict__ s2,
                                               h16* __restrict__ z3,
                                               float* __restrict__ s3) {
  int d, w, va, vb, bi, u; bool big;
  smap(d, big, w, va, vb, bi, u);

  if (big) {
    float mu2[28], inv2[28];
#pragma unroll
    for (int c = 0; c < 28; ++c) {
      mu2[c] = s2[(size_t)c * NS + d];
      inv2[c] = s2[(size_t)(28 + c) * NS + d];
    }
    float sum[7] = {0, 0, 0, 0, 0, 0, 0}, sq[7] = {0, 0, 0, 0, 0, 0, 0};
    const int cobase = 7 * w;
    for (int p = 0; p < 17; ++p) {
      const float g0 = l2g[2 * p], b0 = l2b[2 * p];
      const float g1 = l2g[2 * p + 1], b1 = l2b[2 * p + 1];
      const float g2 = l2g[2 * p + 2], b2 = l2b[2 * p + 2];
      float acc[7] = {0, 0, 0, 0, 0, 0, 0};
#pragma unroll
      for (int ci = 0; ci < 28; ++ci) {
        const h16* bp = z2 + (size_t)(ci * 35 + 2 * p) * NS + d;
        float f0 = (float)bp[0];
        float f1v = (float)bp[NS];
        float f2v = (float)bp[2 * NS];
        float n0 = fmaxf(fmaf((f0 - mu2[ci]) * inv2[ci], g0, b0), 0.f);
        float n1 = fmaxf(fmaf((f1v - mu2[ci]) * inv2[ci], g1, b1), 0.f);
        float n2 = fmaxf(fmaf((f2v - mu2[ci]) * inv2[ci], g2, b2), 0.f);
#pragma unroll
        for (int j = 0; j < 7; ++j) {
          const float* wp = w3 + (cobase + j) * 84 + ci * 3;
          acc[j] = fmaf(n0, wp[0], acc[j]);
          acc[j] = fmaf(n1, wp[1], acc[j]);
          acc[j] = fmaf(n2, wp[2], acc[j]);
        }
      }
#pragma unroll
      for (int j = 0; j < 7; ++j) {
        z3[(size_t)((cobase + j) * 17 + p) * NS + d] = (h16)acc[j];
        sum[j] += acc[j]; sq[j] = fmaf(acc[j], acc[j], sq[j]);
      }
    }
#pragma unroll
    for (int j = 0; j < 7; ++j) {
      const int co = cobase + j;
      float mu = sum[j] * (1.0f / 17.0f);
      float var = sq[j] * (1.0f / 17.0f) - mu * mu;
      s3[(size_t)co * NS + d] = mu;
      s3[(size_t)(28 + co) * NS + d] = rsqrtf(var + 1e-5f);
    }
  } else {
    float mu2[4], inv2[4];
#pragma unroll
    for (int c = 0; c < 4; ++c) {
      mu2[c] = s2[(size_t)(56 + c) * NS + d];
      inv2[c] = s2[(size_t)(60 + c) * NS + d];
    }
    float sum = 0.f, sq = 0.f;
    const int co = w;
    for (int p = 0; p < 17; ++p) {
      const float g0 = l2g[2 * p], b0 = l2b[2 * p];
      const float g1 = l2g[2 * p + 1], b1 = l2b[2 * p + 1];
      const float g2 = l2g[2 * p + 2], b2 = l2b[2 * p + 2];
      float acc = 0.f;
#pragma unroll
      for (int ci = 0; ci < 4; ++ci) {
        const h16* bp = z2 + (size_t)(980 + ci * 35 + 2 * p) * NS + d;
        float f0 = (float)bp[0];
        float f1v = (float)bp[NS];
        float f2v = (float)bp[2 * NS];
        float n0 = fmaxf(fmaf((f0 - mu2[ci]) * inv2[ci], g0, b0), 0.f);
        float n1 = fmaxf(fmaf((f1v - mu2[ci]) * inv2[ci], g1, b1), 0.f);
        float n2 = fmaxf(fmaf((f2v - mu2[ci]) * inv2[ci], g2, b2), 0.f);
        const float* wp = f3 + co * 12 + ci * 3;
        acc = fmaf(n0, wp[0], acc);
        acc = fmaf(n1, wp[1], acc);
        acc = fmaf(n2, wp[2], acc);
      }
      z3[(size_t)(476 + co * 17 + p) * NS + d] = (h16)acc;
      sum += acc; sq = fmaf(acc, acc, sq);
    }
    float mu = sum * (1.0f / 17.0f);
    float var = sq * (1.0f / 17.0f) - mu * mu;
    s3[(size_t)(56 + co) * NS + d] = mu;
    s3[(size_t)(60 + co) * NS + d] = rsqrtf(var + 1e-5f);
  }
}

// -------- k_c4: LN3-apply + conv4 + LN4 + ReLU + final store (z4 in regs) ----
__global__ __launch_bounds__(256, 2) void k_c4(const h16* __restrict__ z3,
                                               const float* __restrict__ w4,
                                               const float* __restrict__ f4,
                                               const float* __restrict__ l3g,
                                               const float* __restrict__ l3b,
                                               const float* __restrict__ l4g,
                                               const float* __restrict__ l4b,
                                               const float* __restrict__ s3,
                                               float* __restrict__ out) {
  int d, w, va, vb, bi, u; bool big;
  smap(d, big, w, va, vb, bi, u);

  if (big) {
    float mu3[28], inv3[28];
#pragma unroll
    for (int c = 0; c < 28; ++c) {
      mu3[c] = s3[(size_t)c * NS + d];
      inv3[c] = s3[(size_t)(28 + c) * NS + d];
    }
    float z4[7][8];
    float sum[7] = {0, 0, 0, 0, 0, 0, 0}, sq[7] = {0, 0, 0, 0, 0, 0, 0};
    const int cobase = 7 * w;
    for (int p = 0; p < 8; ++p) {
      const float g0 = l3g[2 * p], b0 = l3b[2 * p];
      const float g1 = l3g[2 * p + 1], b1 = l3b[2 * p + 1];
      const float g2 = l3g[2 * p + 2], b2 = l3b[2 * p + 2];
      float acc[7] = {0, 0, 0, 0, 0, 0, 0};
#pragma unroll
      for (int ci = 0; ci < 28; ++ci) {
        const h16* bp = z3 + (size_t)(ci * 17 + 2 * p) * NS + d;
        float f0 = (float)bp[0];
        float f1v = (float)bp[NS];
        float f2v = (float)bp[2 * NS];
        float n0 = fmaxf(fmaf((f0 - mu3[ci]) * inv3[ci], g0, b0), 0.f);
        float n1 = fmaxf(fmaf((f1v - mu3[ci]) * inv3[ci], g1, b1), 0.f);
        float n2 = fmaxf(fmaf((f2v - mu3[ci]) * inv3[ci], g2, b2), 0.f);
#pragma unroll
        for (int j = 0; j < 7; ++j) {
          const float* wp = w4 + (cobase + j) * 84 + ci * 3;
          acc[j] = fmaf(n0, wp[0], acc[j]);
          acc[j] = fmaf(n1, wp[1], acc[j]);
          acc[j] = fmaf(n2, wp[2], acc[j]);
        }
      }
#pragma unroll
      for (int j = 0; j < 7; ++j) {
        z4[j][p] = acc[j];
        sum[j] += acc[j]; sq[j] = fmaf(acc[j], acc[j], sq[j]);
      }
    }
#pragma unroll
    for (int j = 0; j < 7; ++j) {
      const int co = cobase + j;
      float mu = sum[j] * 0.125f;
      float var = sq[j] * 0.125f - mu * mu;
      float inv = rsqrtf(var + 1e-5f);
      const int ch = (u < 8) ? co : (28 + co);
      float* op = out + (size_t)bi * 4096 + (size_t)ch * 64 + (size_t)(u & 7) * 8;
      float o[8];
#pragma unroll
      for (int p = 0; p < 8; ++p)
        o[p] = fmaxf(fmaf((z4[j][p] - mu) * inv, l4g[p], l4b[p]), 0.f);
      *(float4*)(op) = make_float4(o[0], o[1], o[2], o[3]);
      *(float4*)(op + 4) = make_float4(o[4], o[5], o[6], o[7]);
    }
  } else {
    float mu3[4], inv3[4];
#pragma unroll
    for (int c = 0; c < 4; ++c) {
      mu3[c] = s3[(size_t)(56 + c) * NS + d];
      inv3[c] = s3[(size_t)(60 + c) * NS + d];
    }
    float z4[8];
    float sum = 0.f, sq = 0.f;
    const int co = w;
    for (int p = 0; p < 8; ++p) {
      const float g0 = l3g[2 * p], b0 = l3b[2 * p];
      const float g1 = l3g[2 * p + 1], b1 = l3b[2 * p + 1];
      const float g2 = l3g[2 * p + 2], b2 = l3b[2 * p + 2];
      float acc = 0.f;
#pragma unroll
      for (int ci = 0; ci < 4; ++ci) {
        const h16* bp = z3 + (size_t)(476 + ci * 17 + 2 * p) * NS + d;
        float f0 = (float)bp[0];
        float f1v = (float)bp[NS];
        float f2v = (float)bp[2 * NS];
        float n0 = fmaxf(fmaf((f0 - mu3[ci]) * inv3[ci], g0, b0), 0.f);
        float n1 = fmaxf(fmaf((f1v - mu3[ci]) * inv3[ci], g1, b1), 0.f);
        float n2 = fmaxf(fmaf((f2v - mu3[ci]) * inv3[ci], g2, b2), 0.f);
        const float* wp = f4 + co * 12 + ci * 3;
        acc = fmaf(n0, wp[0], acc);
        acc = fmaf(n1, wp[1], acc);
        acc = fmaf(n2, wp[2], acc);
      }
      z4[p] = acc;
      sum += acc; sq = fmaf(acc, acc, sq);
    }
    float mu = sum * 0.125f;
    float var = sq * 0.125f - mu * mu;
    float inv = rsqrtf(var + 1e-5f);
    const int ch = (u < 8) ? (56 + co) : (60 + co);
    float* op = out + (size_t)bi * 4096 + (size_t)ch * 64 + (size_t)(u & 7) * 8;
    float o[8];
#pragma unroll
    for (int p = 0; p < 8; ++p)
      o[p] = fmaxf(fmaf((z4[p] - mu) * inv, l4g[p], l4b[p]), 0.f);
    *(float4*)(op) = make_float4(o[0], o[1], o[2], o[3]);
    *(float4*)(op + 4) = make_float4(o[4], o[5], o[6], o[7]);
  }
}

extern "C" void kernel_launch(void* const* d_in, const int* in_sizes, int n_in,
                              void* d_out, int out_size, void* d_ws, size_t ws_size,
                              hipStream_t stream) {
  const float* x   = (const float*)d_in[0];
  const float* w1  = (const float*)d_in[1];
  const float* w2  = (const float*)d_in[2];
  const float* w3  = (const float*)d_in[3];
  const float* w4  = (const float*)d_in[4];
  const float* f1  = (const float*)d_in[5];
  const float* f2  = (const float*)d_in[6];
  const float* f3  = (const float*)d_in[7];
  const float* f4  = (const float*)d_in[8];
  const float* l1g = (const float*)d_in[9];
  const float* l1b = (const float*)d_in[10];
  const float* l2g = (const float*)d_in[11];
  const float* l2b = (const float*)d_in[12];
  const float* l3g = (const float*)d_in[13];
  const float* l3b = (const float*)d_in[14];
  const float* l4g = (const float*)d_in[15];
  const float* l4b = (const float*)d_in[16];
  float* out = (float*)d_out;
  char* wsb = (char*)d_ws;

  // workspace carve (bytes); total 374,686,144 B = 357 MB
  float* xv = (float*)(wsb + 0);                      // [143][VSTR] f32
  h16*   fm = (h16*)(wsb + 74973184ull);              // [143][VSTR] f16
  h16*   z2 = (h16*)(wsb + 112459776ull);             // big [980][NS] + small [140][NS]
  h16*   z3 = (h16*)(wsb + 259260416ull);             // big [476][NS] + small [68][NS]
  float* s1 = (float*)(wsb + 330563584ull);           // 40 rows [NS] f32
  float* s2 = (float*)(wsb + 341049344ull);           // 64 rows
  float* s3 = (float*)(wsb + 357826560ull);           // 64 rows
  float* tw = (float*)(wsb + 374603776ull);           // [72][286] f32

  k_gather<<<4097, 256, 0, stream>>>(x, xv, tw);
  k_dft<<<512, 256, 0, stream>>>(xv, tw, fm);
  k_c1<<<2048, 256, 0, stream>>>(xv, fm, w1, f1, s1);
  k_c2<<<2048, 256, 0, stream>>>(xv, fm, w1, w2, f1, f2, l1g, l1b, s1, z2, s2);
  k_c3<<<2048, 256, 0, stream>>>(z2, w3, f3, l2g, l2b, s2, z3, s3);
  k_c4<<<2048, 256, 0, stream>>>(z3, w4, f4, l3g, l3b, l4g, l4b, s3, out);
}

// Round 6
// 1587.576 us; speedup vs baseline: 2.4116x; 1.5860x over previous
//
#include <hip/hip_runtime.h>
#include <math.h>

typedef _Float16 h16;

#define NS 65536      // samples per class (big / small)
#define VSTR 131072   // xvec/fmag column count (4096 batches * 32 vectors)

// ---------------- k_gather: x -> xvec columns (fp32); block 4096 builds twiddles ----
__global__ __launch_bounds__(256) void k_gather(const float* __restrict__ x,
                                                float* __restrict__ xv,
                                                float* __restrict__ tw) {
  const int b = blockIdx.x;
  if (b < 4096) {
    const float* xb = x + (size_t)b * 9152;
    const int base = b * 32;
    for (int i = threadIdx.x; i < 9152; i += 256) {
      float v = xb[i];
      int c = i >> 6, pos = i & 63;
      if (pos >= 24 && pos < 40)
        xv[(size_t)c * VSTR + base + (pos - 24)] = v;
      int wc = pos & 7;
      if (wc == 3 || wc == 4)
        xv[(size_t)c * VSTR + base + 16 + ((pos >> 3) << 1) + (wc - 3)] = v;
    }
  } else {
    for (int i = threadIdx.x; i < 10296; i += 256) {
      int k = i / 143, n = i - k * 143;
      int e = (k * n) % 143;
      float ang = 6.2831853071795864769f * (float)e / 143.0f;
      float s, c;
      sincosf(ang, &s, &c);
      tw[2 * i] = c;
      tw[2 * i + 1] = s;
    }
  }
}

// ---------------- k_dft: lane = vector, column in VGPRs, uniform twiddles ----
__global__ __launch_bounds__(256, 2) void k_dft(const float* __restrict__ xv,
                                                const float* __restrict__ tw,
                                                h16* __restrict__ fm) {
  const int v = blockIdx.x * 256 + threadIdx.x;
  float xr[143];
#pragma unroll
  for (int n = 0; n < 143; ++n) xr[n] = xv[(size_t)n * VSTR + v];

  for (int k = 0; k < 72; ++k) {
    const float* __restrict__ twk = tw + k * 286;
    float re = 0.f, im = 0.f;
#pragma unroll
    for (int n = 0; n < 143; ++n) {
      re = fmaf(xr[n], twk[2 * n], re);
      im = fmaf(xr[n], twk[2 * n + 1], im);
    }
    float m = sqrtf(re * re + im * im);
    fm[(size_t)k * VSTR + v] = (h16)m;
    if (k) fm[(size_t)(143 - k) * VSTR + v] = (h16)m;
  }
}

// blocks alternate big/small; 64 samples per block (lane = sample), wave = co-group.
__device__ __forceinline__ void smap(int& d, bool& big, int& w, int& va, int& vb,
                                     int& bi, int& u) {
  int lane = threadIdx.x & 63;
  w = __builtin_amdgcn_readfirstlane(threadIdx.x >> 6);
  big = (blockIdx.x & 1) == 0;
  d = ((int)blockIdx.x >> 1) * 64 + lane;
  bi = d >> 4;
  u = d & 15;
  va = (u < 8) ? bi * 32 + ((u >> 2) << 3) + ((u & 3) << 1)
               : bi * 32 + 16 + ((u & 7) << 1);
  vb = va + 1;
}

// ---------------- k_c1: conv1 -> LN1 stats (no z1 store) ----------------
__global__ __launch_bounds__(256, 2) void k_c1(const float* __restrict__ xv,
                                               const h16* __restrict__ fm,
                                               const float* __restrict__ w1,
                                               const float* __restrict__ f1,
                                               float* __restrict__ s1) {
  int d, w, va, vb, bi, u; bool big;
  smap(d, big, w, va, vb, bi, u);

  if (big) {
    float sum[4] = {0, 0, 0, 0}, sq[4] = {0, 0, 0, 0};
    float A0 = xv[va], B0 = xv[vb];
    for (int p = 0; p < 71; ++p) {
      float A1 = xv[(size_t)(2 * p + 1) * VSTR + va];
      float A2 = xv[(size_t)(2 * p + 2) * VSTR + va];
      float B1 = xv[(size_t)(2 * p + 1) * VSTR + vb];
      float B2 = xv[(size_t)(2 * p + 2) * VSTR + vb];
#pragma unroll
      for (int j = 0; j < 4; ++j) {
        const float* wp = w1 + (4 * w + j) * 6;
        float v = A0 * wp[0];
        v = fmaf(A1, wp[1], v); v = fmaf(A2, wp[2], v);
        v = fmaf(B0, wp[3], v); v = fmaf(B1, wp[4], v); v = fmaf(B2, wp[5], v);
        sum[j] += v; sq[j] = fmaf(v, v, sq[j]);
      }
      A0 = A2; B0 = B2;
    }
#pragma unroll
    for (int j = 0; j < 4; ++j) {
      float mu = sum[j] * (1.0f / 71.0f);
      float var = sq[j] * (1.0f / 71.0f) - mu * mu;
      s1[(size_t)(4 * w + j) * NS + d] = mu;
      s1[(size_t)(16 + 4 * w + j) * NS + d] = rsqrtf(var + 1e-5f);
    }
  } else {
    float sum = 0.f, sq = 0.f;
    const float* wp = f1 + w * 6;
    float A0 = (float)fm[va], B0 = (float)fm[vb];
    for (int p = 0; p < 71; ++p) {
      float A1 = (float)fm[(size_t)(2 * p + 1) * VSTR + va];
      float A2 = (float)fm[(size_t)(2 * p + 2) * VSTR + va];
      float B1 = (float)fm[(size_t)(2 * p + 1) * VSTR + vb];
      float B2 = (float)fm[(size_t)(2 * p + 2) * VSTR + vb];
      float v = A0 * wp[0];
      v = fmaf(A1, wp[1], v); v = fmaf(A2, wp[2], v);
      v = fmaf(B0, wp[3], v); v = fmaf(B1, wp[4], v); v = fmaf(B2, wp[5], v);
      sum += v; sq = fmaf(v, v, sq);
      A0 = A2; B0 = B2;
    }
    float mu = sum * (1.0f / 71.0f);
    float var = sq * (1.0f / 71.0f) - mu * mu;
    s1[(size_t)(32 + w) * NS + d] = mu;
    s1[(size_t)(36 + w) * NS + d] = rsqrtf(var + 1e-5f);
  }
}

// -------- k_c2: conv1(recomp) + LN1-apply + conv2 + LN2 stats -> z2 (fp16) ----
__global__ __launch_bounds__(256, 1) void k_c2(const float* __restrict__ xv,
                                               const h16* __restrict__ fm,
                                               const float* __restrict__ w1,
                                               const float* __restrict__ w2,
                                               const float* __restrict__ f1,
                                               const float* __restrict__ f2,
                                               const float* __restrict__ l1g,
                                               const float* __restrict__ l1b,
                                               const float* __restrict__ s1,
                                               h16* __restrict__ z2,
                                               float* __restrict__ s2) {
  int d, w, va, vb, bi, u; bool big;
  smap(d, big, w, va, vb, bi, u);

  if (big) {
    float mu1[16], inv1[16];
#pragma unroll
    for (int c = 0; c < 16; ++c) {
      mu1[c] = s1[(size_t)c * NS + d];
      inv1[c] = s1[(size_t)(16 + c) * NS + d];
    }
    float sum[7] = {0, 0, 0, 0, 0, 0, 0}, sq[7] = {0, 0, 0, 0, 0, 0, 0};
    const int cobase = 7 * w;
    for (int p = 0; p < 35; ++p) {
      float xa[7], xb[7];
#pragma unroll
      for (int t = 0; t < 7; ++t) {
        xa[t] = xv[(size_t)(4 * p + t) * VSTR + va];
        xb[t] = xv[(size_t)(4 * p + t) * VSTR + vb];
      }
      float z1n[3][16];
#pragma unroll
      for (int r = 0; r < 3; ++r) {
        const int ip = 2 * p + r;
        const float gg = l1g[ip], bb = l1b[ip];
#pragma unroll
        for (int c = 0; c < 16; ++c) {
          const float* wp = w1 + c * 6;
          float v = xa[2 * r] * wp[0];
          v = fmaf(xa[2 * r + 1], wp[1], v);
          v = fmaf(xa[2 * r + 2], wp[2], v);
          v = fmaf(xb[2 * r], wp[3], v);
          v = fmaf(xb[2 * r + 1], wp[4], v);
          v = fmaf(xb[2 * r + 2], wp[5], v);
          float n = (v - mu1[c]) * inv1[c];
          z1n[r][c] = fmaxf(fmaf(n, gg, bb), 0.f);
        }
      }
#pragma unroll
      for (int j = 0; j < 7; ++j) {
        const int co = cobase + j;
        const float* wp = w2 + co * 48;
        float acc = 0.f;
#pragma unroll
        for (int ci = 0; ci < 16; ++ci) {
          acc = fmaf(z1n[0][ci], wp[ci * 3 + 0], acc);
          acc = fmaf(z1n[1][ci], wp[ci * 3 + 1], acc);
          acc = fmaf(z1n[2][ci], wp[ci * 3 + 2], acc);
        }
        z2[(size_t)(co * 35 + p) * NS + d] = (h16)acc;
        sum[j] += acc; sq[j] = fmaf(acc, acc, sq[j]);
      }
    }
#pragma unroll
    for (int j = 0; j < 7; ++j) {
      const int co = cobase + j;
      float mu = sum[j] * (1.0f / 35.0f);
      float var = sq[j] * (1.0f / 35.0f) - mu * mu;
      s2[(size_t)co * NS + d] = mu;
      s2[(size_t)(28 + co) * NS + d] = rsqrtf(var + 1e-5f);
    }
  } else {
    float mu1[4], inv1[4];
#pragma unroll
    for (int c = 0; c < 4; ++c) {
      mu1[c] = s1[(size_t)(32 + c) * NS + d];
      inv1[c] = s1[(size_t)(36 + c) * NS + d];
    }
    float sum = 0.f, sq = 0.f;
    const int co = w;
    const float* wpo = f2 + co * 12;
    for (int p = 0; p < 35; ++p) {
      float xa[7], xb[7];
#pragma unroll
      for (int t = 0; t < 7; ++t) {
        xa[t] = (float)fm[(size_t)(4 * p + t) * VSTR + va];
        xb[t] = (float)fm[(size_t)(4 * p + t) * VSTR + vb];
      }
      float acc = 0.f;
#pragma unroll
      for (int r = 0; r < 3; ++r) {
        const int ip = 2 * p + r;
        const float gg = l1g[ip], bb = l1b[ip];
#pragma unroll
        for (int c = 0; c < 4; ++c) {
          const float* wp = f1 + c * 6;
          float v = xa[2 * r] * wp[0];
          v = fmaf(xa[2 * r + 1], wp[1], v);
          v = fmaf(xa[2 * r + 2], wp[2], v);
          v = fmaf(xb[2 * r], wp[3], v);
          v = fmaf(xb[2 * r + 1], wp[4], v);
          v = fmaf(xb[2 * r + 2], wp[5], v);
          float n = (v - mu1[c]) * inv1[c];
          float zr = fmaxf(fmaf(n, gg, bb), 0.f);
          acc = fmaf(zr, wpo[c * 3 + r], acc);
        }
      }
      z2[(size_t)(980 + co * 35 + p) * NS + d] = (h16)acc;
      sum += acc; sq = fmaf(acc, acc, sq);
    }
    float mu = sum * (1.0f / 35.0f);
    float var = sq * (1.0f / 35.0f) - mu * mu;
    s2[(size_t)(56 + co) * NS + d] = mu;
    s2[(size_t)(60 + co) * NS + d] = rsqrtf(var + 1e-5f);
  }
}

// -------- k_c3: LN2 + conv3 + LN3 stats -> z3  (ci-outer, acc in regs) -------
__global__ __launch_bounds__(256, 1) void k_c3(const h16* __restrict__ z2,
                                               const float* __restrict__ w3,
                                               const float* __restrict__ f3,
                                               const float* __restrict__ l2g,
                                               const float* __restrict__ l2b,
                                               const float* __restrict__ s2,
                                               h16* __restrict__ z3,
                                               float* __restrict__ s3) {
  int d, w, va, vb, bi, u; bool big;
  smap(d, big, w, va, vb, bi, u);

  if (big) {
    float acc[7][17];
#pragma unroll
    for (int j = 0; j < 7; ++j)
#pragma unroll
      for (int p = 0; p < 17; ++p) acc[j][p] = 0.f;
    const int cobase = 7 * w;
#pragma unroll 1
    for (int ci = 0; ci < 28; ++ci) {
      float mu = s2[(size_t)ci * NS + d];
      float inv = s2[(size_t)(28 + ci) * NS + d];
      float n[35];
#pragma unroll
      for (int t = 0; t < 35; ++t) {
        float raw = (float)z2[(size_t)(ci * 35 + t) * NS + d];
        n[t] = fmaxf(fmaf((raw - mu) * inv, l2g[t], l2b[t]), 0.f);
      }
#pragma unroll
      for (int j = 0; j < 7; ++j) {
        const float* wp = w3 + (cobase + j) * 84 + ci * 3;
        float w0 = wp[0], w1v = wp[1], w2v = wp[2];
#pragma unroll
        for (int p = 0; p < 17; ++p)
          acc[j][p] = fmaf(n[2 * p], w0,
                      fmaf(n[2 * p + 1], w1v,
                      fmaf(n[2 * p + 2], w2v, acc[j][p])));
      }
    }
#pragma unroll
    for (int j = 0; j < 7; ++j) {
      const int co = cobase + j;
      float sum = 0.f, sq = 0.f;
#pragma unroll
      for (int p = 0; p < 17; ++p) {
        sum += acc[j][p]; sq = fmaf(acc[j][p], acc[j][p], sq);
        z3[(size_t)(co * 17 + p) * NS + d] = (h16)acc[j][p];
      }
      float mu = sum * (1.0f / 17.0f);
      float var = sq * (1.0f / 17.0f) - mu * mu;
      s3[(size_t)co * NS + d] = mu;
      s3[(size_t)(28 + co) * NS + d] = rsqrtf(var + 1e-5f);
    }
  } else {
    float acc[17];
#pragma unroll
    for (int p = 0; p < 17; ++p) acc[p] = 0.f;
    const int co = w;
#pragma unroll 1
    for (int ci = 0; ci < 4; ++ci) {
      float mu = s2[(size_t)(56 + ci) * NS + d];
      float inv = s2[(size_t)(60 + ci) * NS + d];
      float n[35];
#pragma unroll
      for (int t = 0; t < 35; ++t) {
        float raw = (float)z2[(size_t)(980 + ci * 35 + t) * NS + d];
        n[t] = fmaxf(fmaf((raw - mu) * inv, l2g[t], l2b[t]), 0.f);
      }
      const float* wp = f3 + co * 12 + ci * 3;
      float w0 = wp[0], w1v = wp[1], w2v = wp[2];
#pragma unroll
      for (int p = 0; p < 17; ++p)
        acc[p] = fmaf(n[2 * p], w0,
                 fmaf(n[2 * p + 1], w1v,
                 fmaf(n[2 * p + 2], w2v, acc[p])));
    }
    float sum = 0.f, sq = 0.f;
#pragma unroll
    for (int p = 0; p < 17; ++p) {
      sum += acc[p]; sq = fmaf(acc[p], acc[p], sq);
      z3[(size_t)(476 + co * 17 + p) * NS + d] = (h16)acc[p];
    }
    float mu = sum * (1.0f / 17.0f);
    float var = sq * (1.0f / 17.0f) - mu * mu;
    s3[(size_t)(56 + co) * NS + d] = mu;
    s3[(size_t)(60 + co) * NS + d] = rsqrtf(var + 1e-5f);
  }
}

// -------- k_c4: LN3 + conv4 + LN4 + ReLU + store  (ci-outer, z4 in regs) -----
__global__ __launch_bounds__(256, 1) void k_c4(const h16* __restrict__ z3,
                                               const float* __restrict__ w4,
                                               const float* __restrict__ f4,
                                               const float* __restrict__ l3g,
                                               const float* __restrict__ l3b,
                                               const float* __restrict__ l4g,
                                               const float* __restrict__ l4b,
                                               const float* __restrict__ s3,
                                               float* __restrict__ out) {
  int d, w, va, vb, bi, u; bool big;
  smap(d, big, w, va, vb, bi, u);

  if (big) {
    float acc[7][8];
#pragma unroll
    for (int j = 0; j < 7; ++j)
#pragma unroll
      for (int p = 0; p < 8; ++p) acc[j][p] = 0.f;
    const int cobase = 7 * w;
#pragma unroll 1
    for (int ci = 0; ci < 28; ++ci) {
      float mu = s3[(size_t)ci * NS + d];
      float inv = s3[(size_t)(28 + ci) * NS + d];
      float n[17];
#pragma unroll
      for (int t = 0; t < 17; ++t) {
        float raw = (float)z3[(size_t)(ci * 17 + t) * NS + d];
        n[t] = fmaxf(fmaf((raw - mu) * inv, l3g[t], l3b[t]), 0.f);
      }
#pragma unroll
      for (int j = 0; j < 7; ++j) {
        const float* wp = w4 + (cobase + j) * 84 + ci * 3;
        float w0 = wp[0], w1v = wp[1], w2v = wp[2];
#pragma unroll
        for (int p = 0; p < 8; ++p)
          acc[j][p] = fmaf(n[2 * p], w0,
                      fmaf(n[2 * p + 1], w1v,
                      fmaf(n[2 * p + 2], w2v, acc[j][p])));
      }
    }
#pragma unroll
    for (int j = 0; j < 7; ++j) {
      const int co = cobase + j;
      float sum = 0.f, sq = 0.f;
#pragma unroll
      for (int p = 0; p < 8; ++p) { sum += acc[j][p]; sq = fmaf(acc[j][p], acc[j][p], sq); }
      float mu = sum * 0.125f;
      float var = sq * 0.125f - mu * mu;
      float inv = rsqrtf(var + 1e-5f);
      const int ch = (u < 8) ? co : (28 + co);
      float* op = out + (size_t)bi * 4096 + (size_t)ch * 64 + (size_t)(u & 7) * 8;
      float o[8];
#pragma unroll
      for (int p = 0; p < 8; ++p)
        o[p] = fmaxf(fmaf((acc[j][p] - mu) * inv, l4g[p], l4b[p]), 0.f);
      *(float4*)(op) = make_float4(o[0], o[1], o[2], o[3]);
      *(float4*)(op + 4) = make_float4(o[4], o[5], o[6], o[7]);
    }
  } else {
    float acc[8];
#pragma unroll
    for (int p = 0; p < 8; ++p) acc[p] = 0.f;
    const int co = w;
#pragma unroll 1
    for (int ci = 0; ci < 4; ++ci) {
      float mu = s3[(size_t)(56 + ci) * NS + d];
      float inv = s3[(size_t)(60 + ci) * NS + d];
      float n[17];
#pragma unroll
      for (int t = 0; t < 17; ++t) {
        float raw = (float)z3[(size_t)(476 + ci * 17 + t) * NS + d];
        n[t] = fmaxf(fmaf((raw - mu) * inv, l3g[t], l3b[t]), 0.f);
      }
      const float* wp = f4 + co * 12 + ci * 3;
      float w0 = wp[0], w1v = wp[1], w2v = wp[2];
#pragma unroll
      for (int p = 0; p < 8; ++p)
        acc[p] = fmaf(n[2 * p], w0,
                 fmaf(n[2 * p + 1], w1v,
                 fmaf(n[2 * p + 2], w2v, acc[p])));
    }
    float sum = 0.f, sq = 0.f;
#pragma unroll
    for (int p = 0; p < 8; ++p) { sum += acc[p]; sq = fmaf(acc[p], acc[p], sq); }
    float mu = sum * 0.125f;
    float var = sq * 0.125f - mu * mu;
    float inv = rsqrtf(var + 1e-5f);
    const int ch = (u < 8) ? (56 + co) : (60 + co);
    float* op = out + (size_t)bi * 4096 + (size_t)ch * 64 + (size_t)(u & 7) * 8;
    float o[8];
#pragma unroll
    for (int p = 0; p < 8; ++p)
      o[p] = fmaxf(fmaf((acc[p] - mu) * inv, l4g[p], l4b[p]), 0.f);
    *(float4*)(op) = make_float4(o[0], o[1], o[2], o[3]);
    *(float4*)(op + 4) = make_float4(o[4], o[5], o[6], o[7]);
  }
}

extern "C" void kernel_launch(void* const* d_in, const int* in_sizes, int n_in,
                              void* d_out, int out_size, void* d_ws, size_t ws_size,
                              hipStream_t stream) {
  const float* x   = (const float*)d_in[0];
  const float* w1  = (const float*)d_in[1];
  const float* w2  = (const float*)d_in[2];
  const float* w3  = (const float*)d_in[3];
  const float* w4  = (const float*)d_in[4];
  const float* f1  = (const float*)d_in[5];
  const float* f2  = (const float*)d_in[6];
  const float* f3  = (const float*)d_in[7];
  const float* f4  = (const float*)d_in[8];
  const float* l1g = (const float*)d_in[9];
  const float* l1b = (const float*)d_in[10];
  const float* l2g = (const float*)d_in[11];
  const float* l2b = (const float*)d_in[12];
  const float* l3g = (const float*)d_in[13];
  const float* l3b = (const float*)d_in[14];
  const float* l4g = (const float*)d_in[15];
  const float* l4b = (const float*)d_in[16];
  float* out = (float*)d_out;
  char* wsb = (char*)d_ws;

  // workspace carve (bytes); total 374,686,144 B = 357 MB (R3-proven layout)
  float* xv = (float*)(wsb + 0);                      // [143][VSTR] f32
  h16*   fm = (h16*)(wsb + 74973184ull);              // [143][VSTR] f16
  h16*   z2 = (h16*)(wsb + 112459776ull);             // big [980][NS] + small [140][NS]
  h16*   z3 = (h16*)(wsb + 259260416ull);             // big [476][NS] + small [68][NS]
  float* s1 = (float*)(wsb + 330563584ull);           // 40 rows [NS] f32
  float* s2 = (float*)(wsb + 341049344ull);           // 64 rows
  float* s3 = (float*)(wsb + 357826560ull);           // 64 rows
  float* tw = (float*)(wsb + 374603776ull);           // [72][286] f32

  k_gather<<<4097, 256, 0, stream>>>(x, xv, tw);
  k_dft<<<512, 256, 0, stream>>>(xv, tw, fm);
  k_c1<<<2048, 256, 0, stream>>>(xv, fm, w1, f1, s1);
  k_c2<<<2048, 256, 0, stream>>>(xv, fm, w1, w2, f1, f2, l1g, l1b, s1, z2, s2);
  k_c3<<<2048, 256, 0, stream>>>(z2, w3, f3, l2g, l2b, s2, z3, s3);
  k_c4<<<2048, 256, 0, stream>>>(z3, w4, f4, l3g, l3b, l4g, l4b, s3, out);
}